// Round 8
// baseline (551.945 us; speedup 1.0000x reference)
//
#include <hip/hip_runtime.h>
#include <hip/hip_bf16.h>
#include <cstddef>

// ---------------------------------------------------------------------------
// 2-layer GCN: out = A_norm(relu(A_norm(x@W1)+b1) @ W2) + b2
// R8 schedule (overlap independent latency-bound and compute-bound phases):
//   k_init  : zero deg + W1T prep + dummy-row zero
//   k_mega1 : hist(+rank) || GEMM1(unscaled h)      [parity-interleaved]
//   k_scan1 : padded-count scan partials + dinv (fused)
//   k_scan2/3, then
//   k_mega2 : atomic-free CSR scatter || h *= dinv  [parity-interleaved]
//   k_agg1 -> k_gemm2 -> k_agg2 (branchless padded x8 gathers)
// h/h1/h2 bf16.
// ---------------------------------------------------------------------------

#define IN_F 512
#define HID 128
#define NCLS 32

typedef __attribute__((ext_vector_type(8))) short bf16x8;
typedef __attribute__((ext_vector_type(4))) float f32x4;

__device__ __forceinline__ unsigned short f2bf(float f) {
    union { float f; unsigned u; } v; v.f = f;
    unsigned r = v.u + 0x7fff + ((v.u >> 16) & 1);   // RNE
    return (unsigned short)(r >> 16);
}
__device__ __forceinline__ float bf2f(unsigned short h) {
    union { unsigned u; float f; } v; v.u = ((unsigned)h) << 16;
    return v.f;
}
__device__ __forceinline__ float lo16(unsigned u) { return bf2f((unsigned short)(u & 0xffff)); }
__device__ __forceinline__ float hi16(unsigned u) { return bf2f((unsigned short)(u >> 16)); }
__device__ __forceinline__ unsigned sc2(unsigned u, float s) {
    return (unsigned)f2bf(lo16(u) * s) | ((unsigned)f2bf(hi16(u) * s) << 16);
}

// ---------------- init: zero deg + W1T prep + dummy rows ----------------
__global__ void k_init(int* __restrict__ deg, int N,
                       const float* __restrict__ W1, unsigned short* __restrict__ W1T,
                       unsigned* __restrict__ hsu, unsigned* __restrict__ h2su, int ZB) {
    int b = blockIdx.x;
    if (b < ZB) {                      // zero deg via uint4
        int idx = b * 256 + threadIdx.x;
        if (idx * 4 < N) {
            int4 z = make_int4(0, 0, 0, 0);
            if (idx * 4 + 3 < N) *(int4*)(deg + idx * 4) = z;
            else for (int j = idx * 4; j < N; ++j) deg[j] = 0;
        }
    } else if (b < ZB + 256) {         // W1T prep
        int i = (b - ZB) * 256 + threadIdx.x;
        int n = i >> 9, k = i & 511;
        W1T[(size_t)n * IN_F + k] = f2bf(W1[(size_t)k * HID + n]);
    } else {                           // dummy zero rows
        if (threadIdx.x < 64) hsu[(size_t)N * 64 + threadIdx.x] = 0u;
        if (threadIdx.x < 16) h2su[(size_t)N * 16 + threadIdx.x] = 0u;
    }
}

// ---------------- MEGA1: hist+rank (odd blocks) || GEMM1 (even blocks) ----------------
#define LSTR 40
#define SCHUNK 1024
__global__ __launch_bounds__(256) void k_mega1(const float* __restrict__ A,
                                               const unsigned short* __restrict__ BT,
                                               unsigned short* __restrict__ C, int M,
                                               const int* __restrict__ dst,
                                               int* __restrict__ deg, int* __restrict__ rank, int E) {
    const int bid = blockIdx.x;
    const int tid = threadIdx.x;
    if (bid & 1) {
        // ---- hist: rank[e] = deg[dst[e]]++  (4 in flight) ----
        int base = (bid >> 1) * SCHUNK + tid;
        int d[4];
        bool val[4];
#pragma unroll
        for (int j = 0; j < 4; ++j) {
            int e = base + j * 256;
            val[j] = e < E;
            if (val[j]) d[j] = dst[e];
        }
#pragma unroll
        for (int j = 0; j < 4; ++j)
            if (val[j]) rank[base + j * 256] = atomicAdd(&deg[d[j]], 1);
        return;
    }
    // ---- GEMM phase (h unscaled) ----
    __shared__ unsigned short As[64 * LSTR];
    __shared__ unsigned short Bs[128 * LSTR];
    const int wave = tid >> 6;
    const int lane = tid & 63;
    const int l16 = lane & 15;
    const int q = lane >> 4;
    const int rowBase = (bid >> 1) * 64;

    const int ar = tid >> 2, akc = tid & 3;
    const int agr = rowBase + ar;
    const int bn0 = tid >> 2, bn1 = 64 + (tid >> 2), bkc = tid & 3;

    f32x4 acc[8];
#pragma unroll
    for (int nt = 0; nt < 8; ++nt) acc[nt] = (f32x4){0.f, 0.f, 0.f, 0.f};

    float4 pa0, pa1;
    uint4 pb0, pb1;
    auto load_tile = [&](int k0, float4& a0, float4& a1, uint4& b0, uint4& b1) {
        if (agr < M) {
            const float* ap = A + (size_t)agr * IN_F + k0 + akc * 8;
            a0 = *(const float4*)ap;
            a1 = *(const float4*)(ap + 4);
        } else {
            a0 = make_float4(0.f, 0.f, 0.f, 0.f);
            a1 = a0;
        }
        b0 = *(const uint4*)(BT + (size_t)bn0 * IN_F + k0 + bkc * 8);
        b1 = *(const uint4*)(BT + (size_t)bn1 * IN_F + k0 + bkc * 8);
    };

    load_tile(0, pa0, pa1, pb0, pb1);

    for (int t = 0; t < 16; ++t) {
        ushort4 lohalf, hihalf;
        lohalf.x = f2bf(pa0.x); lohalf.y = f2bf(pa0.y); lohalf.z = f2bf(pa0.z); lohalf.w = f2bf(pa0.w);
        hihalf.x = f2bf(pa1.x); hihalf.y = f2bf(pa1.y); hihalf.z = f2bf(pa1.z); hihalf.w = f2bf(pa1.w);
        *(ushort4*)(As + ar * LSTR + akc * 8) = lohalf;
        *(ushort4*)(As + ar * LSTR + akc * 8 + 4) = hihalf;
        *(uint4*)(Bs + bn0 * LSTR + bkc * 8) = pb0;
        *(uint4*)(Bs + bn1 * LSTR + bkc * 8) = pb1;
        __syncthreads();

        float4 na0, na1;
        uint4 nb0, nb1;
        if (t < 15) load_tile((t + 1) * 32, na0, na1, nb0, nb1);

        bf16x8 a_frag = *(const bf16x8*)(As + (wave * 16 + l16) * LSTR + q * 8);
        bf16x8 b_frag[8];
#pragma unroll
        for (int nt = 0; nt < 8; ++nt)
            b_frag[nt] = *(const bf16x8*)(Bs + (nt * 16 + l16) * LSTR + q * 8);
#pragma unroll
        for (int nt = 0; nt < 8; ++nt)
            acc[nt] = __builtin_amdgcn_mfma_f32_16x16x32_bf16(a_frag, b_frag[nt], acc[nt], 0, 0, 0);
        __syncthreads();
        pa0 = na0; pa1 = na1; pb0 = nb0; pb1 = nb1;
    }

#pragma unroll
    for (int r = 0; r < 4; ++r) {
        int row = rowBase + wave * 16 + q * 4 + r;
        if (row < M) {
#pragma unroll
            for (int nt = 0; nt < 8; ++nt)
                C[(size_t)row * HID + nt * 16 + l16] = f2bf(acc[nt][r]);
        }
    }
}

// ---------------- scan1 (padded counts) + dinv fused ----------------
__global__ __launch_bounds__(256) void k_scan1(const int* __restrict__ deg, int* __restrict__ rs,
                                               int* __restrict__ bsum, float* __restrict__ dinv, int n) {
    __shared__ int sd[256];
    int base = blockIdx.x * 2048 + threadIdx.x * 8;
    int v[8];
    int t = 0;
#pragma unroll
    for (int i = 0; i < 8; ++i) {
        int d = (base + i < n) ? deg[base + i] : 0;
        if (base + i < n) dinv[base + i] = rsqrtf((float)d + 1.0f);
        int x = (base + i < n) ? ((d + 7) & ~7) : 0;
        v[i] = t;
        t += x;
    }
    sd[threadIdx.x] = t;
    __syncthreads();
    for (int off = 1; off < 256; off <<= 1) {
        int x = 0;
        if ((int)threadIdx.x >= off) x = sd[threadIdx.x - off];
        __syncthreads();
        if ((int)threadIdx.x >= off) sd[threadIdx.x] += x;
        __syncthreads();
    }
    int texcl = sd[threadIdx.x] - t;
#pragma unroll
    for (int i = 0; i < 8; ++i)
        if (base + i < n) rs[base + i] = texcl + v[i];
    if (threadIdx.x == 255) bsum[blockIdx.x] = sd[255];
}

__global__ void k_scan2(int* bsum, int nb) {
    if (threadIdx.x == 0 && blockIdx.x == 0) {
        int run = 0;
        for (int b = 0; b < nb; ++b) { int t = bsum[b]; bsum[b] = run; run += t; }
    }
}

// finalize rs and fill pad slots of csr with dummy index n (zero row)
__global__ void k_scan3(int* __restrict__ rs, const int* __restrict__ bsum,
                        const int* __restrict__ deg, int* __restrict__ csr, int n) {
    int i = blockIdx.x * 256 + threadIdx.x;
    if (i < n) {
        int r = rs[i] + bsum[i >> 11];
        rs[i] = r;
        int d = deg[i];
        int pc = (d + 7) & ~7;
        for (int j = d; j < pc; ++j) csr[r + j] = n;
    }
}

// ---------------- MEGA2: scatter (odd) || h *= dinv in place (even) ----------------
__global__ __launch_bounds__(256) void k_mega2(const int* __restrict__ src, const int* __restrict__ dst,
                                               const int* __restrict__ rank, const int* __restrict__ rs,
                                               int* __restrict__ csr, int E,
                                               unsigned* __restrict__ hu, const float* __restrict__ dinv,
                                               int N) {
    const int bid = blockIdx.x;
    const int tid = threadIdx.x;
    if (bid & 1) {
        // ---- scatter: csr[rs[dst]+rank] = src, no atomics, 4 chains ----
        int base = (bid >> 1) * SCHUNK + tid;
        int d[4], s[4], rk[4];
        bool val[4];
#pragma unroll
        for (int j = 0; j < 4; ++j) {
            int e = base + j * 256;
            val[j] = e < E;
            if (val[j]) { d[j] = dst[e]; s[j] = src[e]; rk[j] = rank[e]; }
        }
#pragma unroll
        for (int j = 0; j < 4; ++j)
            if (val[j]) csr[rs[d[j]] + rk[j]] = s[j];
        return;
    }
    // ---- scale: rows [g*64, g*64+64), thread -> row g*64+(tid>>2), uint4 quarter tid&3 ----
    int row = (bid >> 1) * 64 + (tid >> 2);
    if (row >= N) return;
    float dv = dinv[row];
    uint4* p = (uint4*)(hu + (size_t)row * 64) + (tid & 3) * 4;
#pragma unroll
    for (int j = 0; j < 4; ++j) {
        uint4 u = p[j];
        u.x = sc2(u.x, dv); u.y = sc2(u.y, dv);
        u.z = sc2(u.z, dv); u.w = sc2(u.w, dv);
        p[j] = u;
    }
}

// ---------------- agg1: one wave per node, branchless padded x8 ----------------
__global__ __launch_bounds__(256) void k_agg1(const unsigned short* __restrict__ hs,
                                              const int* __restrict__ csr,
                                              const int* __restrict__ rs, const int* __restrict__ cnt,
                                              const float* __restrict__ dinv, const float* __restrict__ b1,
                                              unsigned short* __restrict__ h1, int N) {
    int v = blockIdx.x * 4 + (threadIdx.x >> 6);
    if (v >= N) return;
    int lane = threadIdx.x & 63;
    float dv = dinv[v];
    const unsigned* hrow = (const unsigned*)hs;
    unsigned u = hrow[(size_t)v * 64 + lane];   // self (pre-scaled)
    float ax = lo16(u), ay = hi16(u);
    int start = rs[v];
    int pc = (cnt[v] + 7) & ~7;
    for (int i = 0; i < pc; i += 8) {
        int s[8];
        unsigned uu[8];
#pragma unroll
        for (int j = 0; j < 8; ++j) s[j] = csr[start + i + j];
#pragma unroll
        for (int j = 0; j < 8; ++j) uu[j] = hrow[(size_t)s[j] * 64 + lane];
#pragma unroll
        for (int j = 0; j < 8; ++j) { ax += lo16(uu[j]); ay += hi16(uu[j]); }
    }
    float2 bb = ((const float2*)b1)[lane];
    float ox = fmaxf(dv * ax + bb.x, 0.f);
    float oy = fmaxf(dv * ay + bb.y, 0.f);
    ((unsigned*)h1)[(size_t)v * 64 + lane] =
        (unsigned)f2bf(ox) | ((unsigned)f2bf(oy) << 16);
}

// ---------------- GEMM2: h1[M,128]bf16 @ W2[128,32]fp32 -> h2s[M,32]bf16 (dinv-scaled) ----------------
__global__ __launch_bounds__(256) void k_gemm2(const unsigned short* __restrict__ A,
                                               const float* __restrict__ B,
                                               const float* __restrict__ dinv,
                                               unsigned short* __restrict__ C, int M) {
    __shared__ float Bs[HID][NCLS];
    __shared__ float As[64][HID];
    const int tid = threadIdx.x;
#pragma unroll
    for (int it = 0; it < 16; ++it) {
        int idx = tid + 256 * it;
        Bs[idx >> 5][idx & 31] = B[idx];
    }
    int rowBase = blockIdx.x * 64;
    const unsigned* A2 = (const unsigned*)A;
#pragma unroll
    for (int it = 0; it < 16; ++it) {
        int idx = tid + 256 * it;
        int r = idx >> 6, c2 = idx & 63;
        int gr = rowBase + r;
        unsigned u = (gr < M) ? A2[(size_t)gr * 64 + c2] : 0u;
        As[r][2 * c2]     = lo16(u);
        As[r][2 * c2 + 1] = hi16(u);
    }
    __syncthreads();
    int col = tid & 31;
    int rg = tid >> 5;
    float acc[8];
#pragma unroll
    for (int i = 0; i < 8; ++i) acc[i] = 0.f;
    for (int k = 0; k < HID; ++k) {
        float b = Bs[k][col];
#pragma unroll
        for (int i = 0; i < 8; ++i) acc[i] += As[rg * 8 + i][k] * b;
    }
#pragma unroll
    for (int i = 0; i < 8; ++i) {
        int gr = rowBase + rg * 8 + i;
        if (gr < M) C[(size_t)gr * NCLS + col] = f2bf(acc[i] * dinv[gr]);
    }
}

// ---------------- agg2: 16 lanes per node (row = 1 cache line), branchless padded x8 ----------------
__global__ __launch_bounds__(256) void k_agg2(const unsigned short* __restrict__ h2s,
                                              const int* __restrict__ csr,
                                              const int* __restrict__ rs, const int* __restrict__ cnt,
                                              const float* __restrict__ dinv, const float* __restrict__ b2,
                                              float* __restrict__ out, int N) {
    int g = threadIdx.x >> 4;       // node slot 0..15
    int l = threadIdx.x & 15;       // 2 feats per lane
    int v = blockIdx.x * 16 + g;
    if (v >= N) return;
    float dv = dinv[v];
    const unsigned* rows = (const unsigned*)h2s;   // 16 uints per row
    unsigned u = rows[(size_t)v * 16 + l];         // self (pre-scaled)
    float ax = lo16(u), ay = hi16(u);
    int start = rs[v];
    int pc = (cnt[v] + 7) & ~7;
    for (int i = 0; i < pc; i += 8) {
        int s[8];
        unsigned uu[8];
#pragma unroll
        for (int j = 0; j < 8; ++j) s[j] = csr[start + i + j];
#pragma unroll
        for (int j = 0; j < 8; ++j) uu[j] = rows[(size_t)s[j] * 16 + l];
#pragma unroll
        for (int j = 0; j < 8; ++j) { ax += lo16(uu[j]); ay += hi16(uu[j]); }
    }
    float2 bb = ((const float2*)b2)[l];
    float2 o;
    o.x = dv * ax + bb.x;
    o.y = dv * ay + bb.y;
    *((float2*)(out + (size_t)v * NCLS) + l) = o;
}

// ---------------------------------------------------------------------------
extern "C" void kernel_launch(void* const* d_in, const int* in_sizes, int n_in,
                              void* d_out, int out_size, void* d_ws, size_t ws_size,
                              hipStream_t stream) {
    const float* x = (const float*)d_in[0];
    const int* edge_index = (const int*)d_in[1];
    const float* W1 = (const float*)d_in[2];
    const float* b1 = (const float*)d_in[3];
    const float* W2 = (const float*)d_in[4];
    const float* b2 = (const float*)d_in[5];
    float* out = (float*)d_out;

    const int N = in_sizes[0] / IN_F;       // 100000
    const int E = in_sizes[1] / 2;          // 1600000
    const int* e_src = edge_index;
    const int* e_dst = edge_index + E;

    char* ws = (char*)d_ws;
    size_t off = 0;
    auto alloc = [&](size_t bytes) -> char* {
        char* p = ws + off;
        off += (bytes + 255) & ~(size_t)255;
        return p;
    };
    int* deg             = (int*)alloc((size_t)N * 4);
    float* dinv          = (float*)alloc((size_t)N * 4);
    int* rs              = (int*)alloc((size_t)N * 4);
    int* bsum            = (int*)alloc(1024 * 4);
    int* csr             = (int*)alloc(((size_t)E + 8 * (size_t)N) * 4);  // padded CSR
    unsigned short* W1T  = (unsigned short*)alloc((size_t)HID * IN_F * 2);
    unsigned short* hs   = (unsigned short*)alloc((size_t)(N + 1) * HID * 2);  // +1 dummy zero row
    unsigned short* h1   = (unsigned short*)alloc((size_t)N * HID * 2);
    unsigned short* h2s  = (unsigned short*)alloc((size_t)(N + 1) * NCLS * 2); // +1 dummy zero row
    int* rank            = (int*)h1;   // rank dead before agg1 writes h1

    const int nbN = (N + 255) / 256;
    const int nbScan = (N + 2047) / 2048;
    const int ZB = (N / 4 + 255) / 256;         // deg-zero blocks (98)
    const int NBG = (N + 63) / 64;              // 1563 gemm tiles / edge chunks

    k_init<<<ZB + 256 + 1, 256, 0, stream>>>(deg, N, W1, W1T, (unsigned*)hs, (unsigned*)h2s, ZB);
    k_mega1<<<2 * NBG, 256, 0, stream>>>(x, W1T, hs, N, e_dst, deg, rank, E);
    k_scan1<<<nbScan, 256, 0, stream>>>(deg, rs, bsum, dinv, N);
    k_scan2<<<1, 64, 0, stream>>>(bsum, nbScan);
    k_scan3<<<nbN, 256, 0, stream>>>(rs, bsum, deg, csr, N);
    k_mega2<<<2 * NBG, 256, 0, stream>>>(e_src, e_dst, rank, rs, csr, E, (unsigned*)hs, dinv, N);

    k_agg1<<<(N + 3) / 4, 256, 0, stream>>>(hs, csr, rs, deg, dinv, b1, h1, N);
    k_gemm2<<<(N + 63) / 64, 256, 0, stream>>>(h1, W2, dinv, h2s, N);
    k_agg2<<<(N + 15) / 16, 256, 0, stream>>>(h2s, csr, rs, deg, dinv, b2, out, N);
}